// Round 7
// baseline (542.618 us; speedup 1.0000x reference)
//
#include <hip/hip_runtime.h>
#include <math.h>

#define NN     100000
#define NE     1200000
#define D      64
#define BN_EPS 1e-5f
#define CHUNK  8192
#define NCHUNK ((NE + CHUNK - 1) / CHUNK)    // 147
#define NB     ((NN + 511) / 512)            // 196 buckets of 512 nodes
#define CSIZE  (NB * NCHUNK)                 // 28812
#define CAPD   8192                          // max edges per bucket (safety)
#define NCVT   (NN * 16 / 256)               // 6250 cvt blocks

__device__ __forceinline__ float bcastf(float v, int srcLane) {
    return __int_as_float(__builtin_amdgcn_readlane(__float_as_int(v), srcLane));
}
__device__ __forceinline__ unsigned bf16rne(float f) {
    unsigned u = __float_as_uint(f);
    return (u + 0x7FFFu + ((u >> 16) & 1u)) >> 16;
}
__device__ __forceinline__ void acc_bf16(float4& acc, uint2 a) {
    acc.x += __uint_as_float(a.x << 16);
    acc.y += __uint_as_float(a.x & 0xffff0000u);
    acc.z += __uint_as_float(a.y << 16);
    acc.w += __uint_as_float(a.y & 0xffff0000u);
}
// exclusive prefix of s across 256 threads; leaves wave totals in wsum/wexc
// (wexc[3]+wsum[3] == block total after the call).
__device__ __forceinline__ int block_scan_excl(int s, int* wsum, int* wexc) {
    const int lane = threadIdx.x & 63, wid = threadIdx.x >> 6;
    int incl = s;
    #pragma unroll
    for (int off = 1; off < 64; off <<= 1) {
        int n = __shfl_up(incl, off, 64);
        if (lane >= off) incl += n;
    }
    if (lane == 63) wsum[wid] = incl;
    __syncthreads();
    if (threadIdx.x == 0) {
        int r = 0;
        #pragma unroll
        for (int w = 0; w < 4; ++w) { wexc[w] = r; r += wsum[w]; }
    }
    __syncthreads();
    return wexc[wid] + incl - s;
}

// ---------------------------------------------------------------------------
// K1 (fused, block-specialized): blocks [0,NCVT) convert x f32->bf16;
// blocks [NCVT, NCVT+NCHUNK) build per-chunk LDS histograms over NB buckets.
// ---------------------------------------------------------------------------
__global__ __launch_bounds__(256) void cvt_hist_kernel(
        const float4* __restrict__ xv, uint2* __restrict__ xb,
        const int* __restrict__ dst, int* __restrict__ c) {
    const int tid = threadIdx.x;
    if (blockIdx.x < NCVT) {
        const int gid = blockIdx.x * 256 + tid;      // over NN*16 exact
        float4 v = xv[gid];
        uint2 o;
        o.x = bf16rne(v.x) | (bf16rne(v.y) << 16);
        o.y = bf16rne(v.z) | (bf16rne(v.w) << 16);
        xb[gid] = o;
        return;
    }
    __shared__ int hist[256];
    const int i = blockIdx.x - NCVT;                 // chunk id
    const int e0 = i * CHUNK;
    const int n = min(CHUNK, NE - e0);
    hist[tid] = 0;
    __syncthreads();
    for (int k = tid; k < n; k += 256)
        atomicAdd(&hist[dst[e0 + k] >> 9], 1);
    __syncthreads();
    if (tid < NB) c[tid * NCHUNK + i] = hist[tid];
}

// ---------------------------------------------------------------------------
// K2: per-bucket row scan (196 parallel blocks, 147 entries each).
// Row becomes its own exclusive scan (no global base); T[b] = row total.
// ---------------------------------------------------------------------------
__global__ __launch_bounds__(256) void scanA_kernel(
        int* __restrict__ c, int* __restrict__ T) {
    __shared__ int wsum[4], wexc[4];
    int* row = c + blockIdx.x * NCHUNK;
    const int tid = threadIdx.x;
    const int v = (tid < NCHUNK) ? row[tid] : 0;
    const int ex = block_scan_excl(v, wsum, wexc);
    if (tid < NCHUNK) row[tid] = ex;
    if (tid == 0) T[blockIdx.x] = wexc[3] + wsum[3];
}

// ---------------------------------------------------------------------------
// K3: scan the 196 bucket totals -> bucket starts S[0..NB], S[NB]=NE.
// ---------------------------------------------------------------------------
__global__ __launch_bounds__(256) void scanB_kernel(
        const int* __restrict__ T, int* __restrict__ S) {
    __shared__ int wsum[4], wexc[4];
    const int tid = threadIdx.x;
    const int v = (tid < NB) ? T[tid] : 0;
    const int ex = block_scan_excl(v, wsum, wexc);
    if (tid < NB) S[tid] = ex;
    if (tid == NB) S[NB] = wexc[3] + wsum[3];        // == NE
}

// ---------------------------------------------------------------------------
// K4: each block locally sorts its 8192-edge chunk by bucket in LDS, then
// writes bucket-contiguous runs to `binned`. Record = (src<<9)|(dst&511).
// ---------------------------------------------------------------------------
__global__ __launch_bounds__(256) void chunk_scatter_kernel(
        const int* __restrict__ src, const int* __restrict__ dst,
        const int* __restrict__ c, const int* __restrict__ S,
        int* __restrict__ binned) {
    __shared__ int hist[256];            // local bucket start
    __shared__ int lcur[256];
    __shared__ int cbaseL[256];
    __shared__ int sorted[CHUNK];        // 32 KB
    __shared__ unsigned char bOf[CHUNK]; // 8 KB
    __shared__ int wsum[4], wexc[4];
    const int tid = threadIdx.x;
    const int i = blockIdx.x;
    const int e0 = i * CHUNK;
    const int n = min(CHUNK, NE - e0);

    hist[tid] = 0;
    if (tid < NB) cbaseL[tid] = c[tid * NCHUNK + i] + S[tid];
    __syncthreads();
    for (int k = tid; k < n; k += 256)
        atomicAdd(&hist[dst[e0 + k] >> 9], 1);
    __syncthreads();
    const int h = hist[tid];
    const int ex = block_scan_excl(h, wsum, wexc);
    hist[tid] = ex;
    lcur[tid] = ex;
    __syncthreads();
    for (int k = tid; k < n; k += 256) {
        const int dv = dst[e0 + k];
        const int b = dv >> 9;
        const int slot = atomicAdd(&lcur[b], 1);
        sorted[slot] = (src[e0 + k] << 9) | (dv & 511);
        bOf[slot] = (unsigned char)b;
    }
    __syncthreads();
    for (int k = tid; k < n; k += 256) {
        const int b = bOf[k];
        binned[cbaseL[b] + (k - hist[b])] = sorted[k];
    }
}

// ---------------------------------------------------------------------------
// K5: per-bucket counting sort fully in LDS -> start[] + srcSorted.
// ---------------------------------------------------------------------------
__global__ __launch_bounds__(256) void bucket_csr_kernel(
        const int* __restrict__ binned, const int* __restrict__ S,
        int* __restrict__ start, int* __restrict__ srcSorted) {
    __shared__ int lhist[512];
    __shared__ int lcur[512];
    __shared__ int sortedS[CAPD];        // 32 KB
    __shared__ int wsum[4], wexc[4];
    const int tid = threadIdx.x;
    const int b = blockIdx.x;
    const int n0 = b * 512;
    const int nb = min(512, NN - n0);
    const int lo = S[b];
    const int hi = S[b + 1];
    int cnt = hi - lo;
    if (cnt > CAPD) cnt = CAPD;          // impossible for this input; no OOB

    lhist[tid] = 0; lhist[tid + 256] = 0;
    __syncthreads();
    for (int k = tid; k < cnt; k += 256)
        atomicAdd(&lhist[binned[lo + k] & 511], 1);
    __syncthreads();
    const int h0 = lhist[2 * tid], h1 = lhist[2 * tid + 1];
    const int ex = block_scan_excl(h0 + h1, wsum, wexc);
    lhist[2 * tid] = ex;      lhist[2 * tid + 1] = ex + h0;
    lcur[2 * tid] = ex;       lcur[2 * tid + 1] = ex + h0;
    __syncthreads();
    for (int l = tid; l < nb; l += 256) start[n0 + l] = lo + lhist[l];
    if (b == NB - 1 && tid == 0) start[NN] = NE;
    for (int k = tid; k < cnt; k += 256) {
        const int rec = binned[lo + k];
        const int slot = atomicAdd(&lcur[rec & 511], 1);
        sortedS[slot] = rec >> 9;
    }
    __syncthreads();
    for (int k = tid; k < cnt; k += 256) srcSorted[lo + k] = sortedS[k];
}

// ---------------------------------------------------------------------------
// K6: fused gather(bf16) -> mean -> @W -> ELU -> h + BN-stat partials.
// Quarter-wave (16 lanes) per node; R5-proven inner body (4 loads in
// flight, VGPR~60). Wave-level work stealing: lane 0 atomicAdd + uniform
// readfirstlane broadcast — NO barriers in the main loop (R6 lesson:
// block-wide barriers lockstep the waves and collapse load ILP).
// ---------------------------------------------------------------------------
__global__ __launch_bounds__(256) void agg_gemm_kernel(
        const uint2* __restrict__ xb,           // [NN][16] uint2 (bf16 rows)
        const int*   __restrict__ start,
        const int*   __restrict__ srcSorted,
        const float* __restrict__ W,            // [D_IN, D_OUT] row-major
        float* __restrict__ h,
        float* __restrict__ stats,              // [0..63]=sum, [64..127]=sumsq
        int* __restrict__ ctr) {
    __shared__ float4 Wt2[16 * 64];             // [k0][c] = W[4k0..4k0+3][c]
    __shared__ float red[2][256];

    for (int i = threadIdx.x; i < D * D; i += 256) {
        const float val = W[i];
        const int k = i >> 6, cc = i & 63;
        ((float*)&Wt2[(k >> 2) * 64 + cc])[k & 3] = val;
    }
    __syncthreads();                            // Wt2 ready; no syncs after

    const int lane = threadIdx.x & 63;
    const int q    = lane >> 4;                 // quarter-wave = node slot
    const int t    = lane & 15;                 // uint2 slot within row

    float s = 0.f, s2 = 0.f;
    const int nSteal = NN / 4;                  // 25000 4-node groups
    for (;;) {
        int itS;
        if (lane == 0) itS = atomicAdd(ctr, 1);
        const int it = __builtin_amdgcn_readfirstlane(itS);
        if (it >= nSteal) break;

        const int node = it * 4 + q;
        const int e0 = start[node], e1 = start[node + 1];
        float4 acc = make_float4(0.f, 0.f, 0.f, 0.f);
        int j = e0;
        for (; j + 4 <= e1; j += 4) {           // 4 rows in flight per lane
            const int s0 = srcSorted[j];
            const int s1 = srcSorted[j + 1];
            const int s2i = srcSorted[j + 2];
            const int s3 = srcSorted[j + 3];
            const uint2 a0 = xb[(size_t)s0 * 16 + t];
            const uint2 a1 = xb[(size_t)s1 * 16 + t];
            const uint2 a2 = xb[(size_t)s2i * 16 + t];
            const uint2 a3 = xb[(size_t)s3 * 16 + t];
            acc_bf16(acc, a0);
            acc_bf16(acc, a1);
            acc_bf16(acc, a2);
            acc_bf16(acc, a3);
        }
        for (; j < e1; ++j) {
            const int s0 = srcSorted[j];
            acc_bf16(acc, xb[(size_t)s0 * 16 + t]);
        }
        const float deg = (float)(e1 - e0);

        // GEMM: 4 nodes per wave, broadcast via readlane (uniform lane ids)
        #pragma unroll
        for (int qq = 0; qq < 4; ++qq) {
            float hacc = 0.f;
            #pragma unroll
            for (int k0 = 0; k0 < 16; ++k0) {
                const float4 wv = Wt2[k0 * 64 + lane];
                const int srcL = qq * 16 + k0;
                hacc = fmaf(bcastf(acc.x, srcL), wv.x, hacc);
                hacc = fmaf(bcastf(acc.y, srcL), wv.y, hacc);
                hacc = fmaf(bcastf(acc.z, srcL), wv.z, hacc);
                hacc = fmaf(bcastf(acc.w, srcL), wv.w, hacc);
            }
            const float invq = 1.0f / fmaxf(bcastf(deg, qq * 16), 1.0f);
            hacc *= invq;                       // (agg*inv)@W == inv*(agg@W)
            const float hv = hacc > 0.f ? hacc : expm1f(hacc);
            const int nodeq = it * 4 + qq;
            h[(size_t)nodeq * 64 + lane] = hv;
            s  += hv;
            s2 += hv * hv;
        }
    }

    red[0][threadIdx.x] = s;
    red[1][threadIdx.x] = s2;
    __syncthreads();
    if (threadIdx.x < 64) {
        float ts  = red[0][threadIdx.x] + red[0][threadIdx.x + 64] +
                    red[0][threadIdx.x + 128] + red[0][threadIdx.x + 192];
        float ts2 = red[1][threadIdx.x] + red[1][threadIdx.x + 64] +
                    red[1][threadIdx.x + 128] + red[1][threadIdx.x + 192];
        atomicAdd(&stats[threadIdx.x],      ts);
        atomicAdd(&stats[64 + threadIdx.x], ts2);
    }
}

// ---------------------------------------------------------------------------
// K7: BatchNorm finalize, float4-vectorized streaming.
// ---------------------------------------------------------------------------
__global__ __launch_bounds__(256) void bn_kernel(
        const float4* __restrict__ h,
        const float*  __restrict__ stats,
        const float*  __restrict__ gamma,
        const float*  __restrict__ beta,
        float4* __restrict__ out) {
    int gid = blockIdx.x * 256 + threadIdx.x;     // over NN*D/4 exact
    const int c0 = (gid & 15) * 4;
    const float4 v = h[gid];
    float4 r;
    const float* vv = (const float*)&v;
    float* rr = (float*)&r;
    #pragma unroll
    for (int k = 0; k < 4; ++k) {
        const int c = c0 + k;
        const float mu  = stats[c] * (1.0f / NN);
        const float var = stats[64 + c] * (1.0f / NN) - mu * mu;
        const float is  = rsqrtf(var + BN_EPS);
        rr[k] = (vv[k] - mu) * is * gamma[c] + beta[c];
    }
    out[gid] = r;
}

extern "C" void kernel_launch(void* const* d_in, const int* in_sizes, int n_in,
                              void* d_out, int out_size, void* d_ws, size_t ws_size,
                              hipStream_t stream) {
    const float* x     = (const float*)d_in[0];
    const int*   ei    = (const int*)  d_in[1];
    const float* W     = (const float*)d_in[2];
    const float* gamma = (const float*)d_in[3];
    const float* beta  = (const float*)d_in[4];
    float* out = (float*)d_out;

    // workspace layout (4B units):
    // [buf NN*D (binned NE overlays head during build)]
    // [stats 128][ctr 4][start NN+4][c CSIZE][T 256][S 256]
    // [srcSorted NE][xb NN*16 uint2]
    float* buf       = (float*)d_ws;
    int*   binned    = (int*)buf;                    // dead before agg_gemm
    float* stats     = buf + (size_t)NN * D;
    int*   ctr       = (int*)(stats + 128);
    int*   start     = ctr + 4;
    int*   c         = start + NN + 4;
    int*   T         = c + CSIZE;
    int*   S         = T + 256;
    int*   srcSorted = S + 256;
    uint2* xb        = (uint2*)(srcSorted + NE);

    // zero stats + work-steal counter (contiguous)
    hipMemsetAsync(stats, 0, 132 * sizeof(int), stream);

    cvt_hist_kernel  <<<NCVT + NCHUNK, 256, 0, stream>>>(
        (const float4*)x, xb, ei + NE, c);
    scanA_kernel     <<<NB, 256, 0, stream>>>(c, T);
    scanB_kernel     <<<1, 256, 0, stream>>>(T, S);
    chunk_scatter_kernel<<<NCHUNK, 256, 0, stream>>>(ei, ei + NE, c, S, binned);
    bucket_csr_kernel<<<NB, 256, 0, stream>>>(binned, S, start, srcSorted);
    agg_gemm_kernel  <<<2048, 256, 0, stream>>>(
        xb, start, srcSorted, W, buf, stats, ctr);
    bn_kernel        <<<NN * D / 4 / 256, 256, 0, stream>>>(
        (const float4*)buf, stats, gamma, beta, (float4*)out);
}

// Round 8
// 223.819 us; speedup vs baseline: 2.4244x; 2.4244x over previous
//
#include <hip/hip_runtime.h>
#include <math.h>

#define NN     100000
#define NE     1200000
#define D      64
#define BN_EPS 1e-5f
#define CHUNK  8192
#define NCHUNK ((NE + CHUNK - 1) / CHUNK)    // 147
#define NB     ((NN + 511) / 512)            // 196 buckets of 512 nodes
#define CAPD   8192                          // fixed capacity per bucket
#define NCVT   (NN * 16 / 256)               // 6250 cvt blocks

__device__ __forceinline__ float bcastf(float v, int srcLane) {
    return __int_as_float(__builtin_amdgcn_readlane(__float_as_int(v), srcLane));
}
__device__ __forceinline__ unsigned bf16rne(float f) {
    unsigned u = __float_as_uint(f);
    return (u + 0x7FFFu + ((u >> 16) & 1u)) >> 16;
}
__device__ __forceinline__ void acc_bf16(float4& acc, uint2 a) {
    acc.x += __uint_as_float(a.x << 16);
    acc.y += __uint_as_float(a.x & 0xffff0000u);
    acc.z += __uint_as_float(a.y << 16);
    acc.w += __uint_as_float(a.y & 0xffff0000u);
}
// exclusive prefix of s across 256 threads (all threads must call).
__device__ __forceinline__ int block_scan_excl(int s, int* wsum, int* wexc) {
    const int lane = threadIdx.x & 63, wid = threadIdx.x >> 6;
    int incl = s;
    #pragma unroll
    for (int off = 1; off < 64; off <<= 1) {
        int n = __shfl_up(incl, off, 64);
        if (lane >= off) incl += n;
    }
    if (lane == 63) wsum[wid] = incl;
    __syncthreads();
    if (threadIdx.x == 0) {
        int r = 0;
        #pragma unroll
        for (int w = 0; w < 4; ++w) { wexc[w] = r; r += wsum[w]; }
    }
    __syncthreads();
    return wexc[wid] + incl - s;
}

// ---------------------------------------------------------------------------
// K1 (fused, block-specialized): blocks [0,NCVT) convert x f32->bf16.
// Blocks [NCVT, NCVT+NCHUNK): per-chunk LDS histogram -> local bucket sort
// in LDS -> reserve per-bucket space via ONE global atomicAdd per touched
// bucket -> write bucket-contiguous runs into fixed-capacity regions
// srcSorted[b*CAPD ...]. Replaces hist+scanA+scanB+chunk_scatter.
// ---------------------------------------------------------------------------
__global__ __launch_bounds__(256) void cvt_binsort_kernel(
        const float4* __restrict__ xv, uint2* __restrict__ xb,
        const int* __restrict__ src, const int* __restrict__ dst,
        int* __restrict__ cursor, int* __restrict__ binned) {
    const int tid = threadIdx.x;
    if (blockIdx.x < NCVT) {
        const int gid = blockIdx.x * 256 + tid;      // over NN*16 exact
        float4 v = xv[gid];
        uint2 o;
        o.x = bf16rne(v.x) | (bf16rne(v.y) << 16);
        o.y = bf16rne(v.z) | (bf16rne(v.w) << 16);
        xb[gid] = o;
        return;
    }
    __shared__ int histEx[256];          // counts, then local exclusive base
    __shared__ int lcur[256];
    __shared__ int gbase[256];
    __shared__ int sorted[CHUNK];        // 32 KB
    __shared__ unsigned char bOf[CHUNK]; // 8 KB
    __shared__ int wsum[4], wexc[4];
    const int i = blockIdx.x - NCVT;     // chunk id
    const int e0 = i * CHUNK;
    const int n = min(CHUNK, NE - e0);

    histEx[tid] = 0;
    __syncthreads();
    for (int k = tid; k < n; k += 256)
        atomicAdd(&histEx[dst[e0 + k] >> 9], 1);
    __syncthreads();
    const int cnt = histEx[tid];                     // own slot
    const int ex = block_scan_excl(cnt, wsum, wexc);
    histEx[tid] = ex;
    lcur[tid] = ex;
    if (tid < NB && cnt > 0)
        gbase[tid] = atomicAdd(&cursor[tid], cnt);   // reserve run space
    __syncthreads();
    for (int k = tid; k < n; k += 256) {
        const int dv = dst[e0 + k];
        const int b = dv >> 9;
        const int slot = atomicAdd(&lcur[b], 1);
        sorted[slot] = (src[e0 + k] << 9) | (dv & 511);
        bOf[slot] = (unsigned char)b;
    }
    __syncthreads();
    for (int k = tid; k < n; k += 256) {
        const int b = bOf[k];
        binned[b * CAPD + gbase[b] + (k - histEx[b])] = sorted[k];
    }
}

// ---------------------------------------------------------------------------
// K2: per-bucket counting sort fully in LDS, IN PLACE on the fixed-capacity
// region -> srcSorted (plain src ids) + s_arr/e_arr per node.
// ---------------------------------------------------------------------------
__global__ __launch_bounds__(256) void bucket_csr_kernel(
        int* __restrict__ binned, const int* __restrict__ cursor,
        int* __restrict__ s_arr, int* __restrict__ e_arr) {
    __shared__ int lhist[512];
    __shared__ int lcur[512];
    __shared__ int sortedS[CAPD];        // 32 KB
    __shared__ int wsum[4], wexc[4];
    const int tid = threadIdx.x;
    const int b = blockIdx.x;
    const int n0 = b * 512;
    const int nb = min(512, NN - n0);
    const int lo = b * CAPD;
    const int cnt = min(cursor[b], CAPD);

    lhist[tid] = 0; lhist[tid + 256] = 0;
    __syncthreads();
    for (int k = tid; k < cnt; k += 256)
        atomicAdd(&lhist[binned[lo + k] & 511], 1);
    __syncthreads();
    const int h0 = lhist[2 * tid], h1 = lhist[2 * tid + 1];
    const int ex = block_scan_excl(h0 + h1, wsum, wexc);
    // CSR bounds for the two nodes this thread owns
    const int l0 = 2 * tid, l1 = 2 * tid + 1;
    if (l0 < nb) { s_arr[n0 + l0] = lo + ex;      e_arr[n0 + l0] = lo + ex + h0; }
    if (l1 < nb) { s_arr[n0 + l1] = lo + ex + h0; e_arr[n0 + l1] = lo + ex + h0 + h1; }
    lcur[l0] = ex;
    lcur[l1] = ex + h0;
    __syncthreads();
    for (int k = tid; k < cnt; k += 256) {
        const int rec = binned[lo + k];
        const int slot = atomicAdd(&lcur[rec & 511], 1);
        sortedS[slot] = rec >> 9;
    }
    __syncthreads();
    for (int k = tid; k < cnt; k += 256) binned[lo + k] = sortedS[k];
}

// ---------------------------------------------------------------------------
// K3: fused gather(bf16) -> mean -> @W -> ELU -> h + BN-stat partials.
// EXACT structure of the bench-proven 92.6us version (R5 profile: VGPR 60):
// grid-stride over 16-node groups, quarter-wave per node, simple 4-wide
// gather, readlane-broadcast GEMM. (Steal variants collapse VGPR to 24 and
// serialize the loads — do not reintroduce.)
// ---------------------------------------------------------------------------
__global__ __launch_bounds__(256) void agg_gemm_kernel(
        const uint2* __restrict__ xb,           // [NN][16] uint2 (bf16 rows)
        const int*   __restrict__ s_arr,
        const int*   __restrict__ e_arr,
        const int*   __restrict__ srcSorted,
        const float* __restrict__ W,            // [D_IN, D_OUT] row-major
        float* __restrict__ h,
        float* __restrict__ stats) {            // [0..63]=sum, [64..127]=sumsq
    __shared__ float4 Wt2[16 * 64];             // [k0][c] = W[4k0..4k0+3][c]
    __shared__ float red[2][256];

    for (int i = threadIdx.x; i < D * D; i += 256) {
        const float val = W[i];
        const int k = i >> 6, cc = i & 63;
        ((float*)&Wt2[(k >> 2) * 64 + cc])[k & 3] = val;
    }
    __syncthreads();

    const int w    = threadIdx.x >> 6;          // wave slot 0..3
    const int lane = threadIdx.x & 63;
    const int q    = lane >> 4;                 // quarter-wave = node slot
    const int t    = lane & 15;                 // uint2 slot within row

    float s = 0.f, s2 = 0.f;
    const int nIter = NN / 16;                  // 6250, exact
    for (int it = blockIdx.x; it < nIter; it += gridDim.x) {
        const int node = it * 16 + w * 4 + q;
        const int e0 = s_arr[node], e1 = e_arr[node];
        float4 acc = make_float4(0.f, 0.f, 0.f, 0.f);
        int j = e0;
        for (; j + 4 <= e1; j += 4) {           // 4 rows in flight per lane
            const int s0 = srcSorted[j];
            const int s1 = srcSorted[j + 1];
            const int s2i = srcSorted[j + 2];
            const int s3 = srcSorted[j + 3];
            const uint2 a0 = xb[(size_t)s0 * 16 + t];
            const uint2 a1 = xb[(size_t)s1 * 16 + t];
            const uint2 a2 = xb[(size_t)s2i * 16 + t];
            const uint2 a3 = xb[(size_t)s3 * 16 + t];
            acc_bf16(acc, a0);
            acc_bf16(acc, a1);
            acc_bf16(acc, a2);
            acc_bf16(acc, a3);
        }
        for (; j < e1; ++j) {
            const int s0 = srcSorted[j];
            acc_bf16(acc, xb[(size_t)s0 * 16 + t]);
        }
        const float deg = (float)(e1 - e0);

        // GEMM: 4 nodes per wave, broadcast via readlane (uniform lane ids)
        #pragma unroll
        for (int qq = 0; qq < 4; ++qq) {
            float hacc = 0.f;
            #pragma unroll
            for (int k0 = 0; k0 < 16; ++k0) {
                const float4 wv = Wt2[k0 * 64 + lane];
                const int srcL = qq * 16 + k0;
                hacc = fmaf(bcastf(acc.x, srcL), wv.x, hacc);
                hacc = fmaf(bcastf(acc.y, srcL), wv.y, hacc);
                hacc = fmaf(bcastf(acc.z, srcL), wv.z, hacc);
                hacc = fmaf(bcastf(acc.w, srcL), wv.w, hacc);
            }
            const float invq = 1.0f / fmaxf(bcastf(deg, qq * 16), 1.0f);
            hacc *= invq;                       // (agg*inv)@W == inv*(agg@W)
            const float hv = hacc > 0.f ? hacc : expm1f(hacc);
            const int nodeq = it * 16 + w * 4 + qq;
            h[(size_t)nodeq * 64 + lane] = hv;
            s  += hv;
            s2 += hv * hv;
        }
    }

    red[0][threadIdx.x] = s;
    red[1][threadIdx.x] = s2;
    __syncthreads();
    if (threadIdx.x < 64) {
        float ts  = red[0][threadIdx.x] + red[0][threadIdx.x + 64] +
                    red[0][threadIdx.x + 128] + red[0][threadIdx.x + 192];
        float ts2 = red[1][threadIdx.x] + red[1][threadIdx.x + 64] +
                    red[1][threadIdx.x + 128] + red[1][threadIdx.x + 192];
        atomicAdd(&stats[threadIdx.x],      ts);
        atomicAdd(&stats[64 + threadIdx.x], ts2);
    }
}

// ---------------------------------------------------------------------------
// K4: BatchNorm finalize, float4-vectorized streaming.
// ---------------------------------------------------------------------------
__global__ __launch_bounds__(256) void bn_kernel(
        const float4* __restrict__ h,
        const float*  __restrict__ stats,
        const float*  __restrict__ gamma,
        const float*  __restrict__ beta,
        float4* __restrict__ out) {
    int gid = blockIdx.x * 256 + threadIdx.x;     // over NN*D/4 exact
    const int c0 = (gid & 15) * 4;
    const float4 v = h[gid];
    float4 r;
    const float* vv = (const float*)&v;
    float* rr = (float*)&r;
    #pragma unroll
    for (int k = 0; k < 4; ++k) {
        const int c = c0 + k;
        const float mu  = stats[c] * (1.0f / NN);
        const float var = stats[64 + c] * (1.0f / NN) - mu * mu;
        const float is  = rsqrtf(var + BN_EPS);
        rr[k] = (vv[k] - mu) * is * gamma[c] + beta[c];
    }
    out[gid] = r;
}

extern "C" void kernel_launch(void* const* d_in, const int* in_sizes, int n_in,
                              void* d_out, int out_size, void* d_ws, size_t ws_size,
                              hipStream_t stream) {
    const float* x     = (const float*)d_in[0];
    const int*   ei    = (const int*)  d_in[1];
    const float* W     = (const float*)d_in[2];
    const float* gamma = (const float*)d_in[3];
    const float* beta  = (const float*)d_in[4];
    float* out = (float*)d_out;

    // workspace layout (4B units):
    // [buf NN*D][stats 128][cursor 256][s_arr NN+pad][e_arr NN+pad]
    // [srcSorted NB*CAPD][xb NN*16 uint2]            total ~45.7 MB
    float* buf       = (float*)d_ws;
    float* stats     = buf + (size_t)NN * D;
    int*   cursor    = (int*)(stats + 128);
    int*   s_arr     = cursor + 256;
    int*   e_arr     = s_arr + NN + 352;             // pad to keep 8B align
    int*   srcSorted = e_arr + NN + 352;
    uint2* xb        = (uint2*)(srcSorted + (size_t)NB * CAPD);

    // zero stats + bucket cursors (contiguous)
    hipMemsetAsync(stats, 0, 384 * sizeof(int), stream);

    cvt_binsort_kernel<<<NCVT + NCHUNK, 256, 0, stream>>>(
        (const float4*)x, xb, ei, ei + NE, cursor, srcSorted);
    bucket_csr_kernel <<<NB, 256, 0, stream>>>(srcSorted, cursor, s_arr, e_arr);
    agg_gemm_kernel   <<<2048, 256, 0, stream>>>(
        xb, s_arr, e_arr, srcSorted, W, buf, stats);
    bn_kernel         <<<NN * D / 4 / 256, 256, 0, stream>>>(
        (const float4*)buf, stats, gamma, beta, (float4*)out);
}